// Round 10
// baseline (300.583 us; speedup 1.0000x reference)
//
#include <hip/hip_runtime.h>

// HoloGraphBlockV7 — round 10: LDS-free direct-fragment GEMM.
// MFMA fragments loaded straight from global (L2-hot), per-wave tiles,
// 64-thread blocks, no barriers/DMA. l2norm epilogue via shfl only.
// Scan / LN / prep unchanged from round 9.

typedef unsigned short u16;
typedef unsigned int u32;
typedef __attribute__((ext_vector_type(8))) short short8;
typedef __attribute__((ext_vector_type(4))) float floatx4;

__device__ __forceinline__ float b2f(u16 u) {
  u32 x = ((u32)u) << 16;
  return __uint_as_float(x);
}
__device__ __forceinline__ u16 f2b(float f) {
  u32 x = __float_as_uint(f);
  u32 r = (x + 0x7fffu + ((x >> 16) & 1u)) >> 16;
  return (u16)r;
}
__device__ __forceinline__ float4 b4_to_f4(uint2 u) {
  float4 r;
  r.x = __uint_as_float((u.x & 0xffffu) << 16);
  r.y = __uint_as_float(u.x & 0xffff0000u);
  r.z = __uint_as_float((u.y & 0xffffu) << 16);
  r.w = __uint_as_float(u.y & 0xffff0000u);
  return r;
}

// ---------------------------------------------------------------------------
// LayerNorm of one 512-row; 256 threads.
__device__ __forceinline__ void ln_row(const float* __restrict__ xr,
                                       const float* __restrict__ g,
                                       const float* __restrict__ bt,
                                       u16* __restrict__ yr, int tid, float* red) {
  float x0 = xr[tid], x1 = xr[tid + 256];
  float s = x0 + x1, ss = x0 * x0 + x1 * x1;
#pragma unroll
  for (int o = 32; o > 0; o >>= 1) { s += __shfl_xor(s, o); ss += __shfl_xor(ss, o); }
  if ((tid & 63) == 0) { red[tid >> 6] = s; red[4 + (tid >> 6)] = ss; }
  __syncthreads();
  float ts = red[0] + red[1] + red[2] + red[3];
  float tss = red[4] + red[5] + red[6] + red[7];
  float mu = ts * (1.f / 512.f);
  float var = tss * (1.f / 512.f) - mu * mu;
  float rstd = 1.0f / sqrtf(var + 1e-5f);
  yr[tid] = f2b((x0 - mu) * rstd * g[tid] + bt[tid]);
  yr[tid + 256] = f2b((x1 - mu) * rstd * g[tid + 256] + bt[tid + 256]);
}

// ---------------------------------------------------------------------------
// Prep: weight transposes f32->bf16 (0..3327), gate/bias pack (3328..3391),
// LN1 rows (3392..5439).
__global__ __launch_bounds__(256) void prep_weights(
    const float* __restrict__ Wk, const float* __restrict__ Wq,
    const float* __restrict__ Wv, const float* __restrict__ Wo,
    const float* __restrict__ Wps, const float* __restrict__ W1,
    const float* __restrict__ W2, const float* __restrict__ Wd,
    const float* __restrict__ Wgw, const float* __restrict__ Wgf,
    const float* __restrict__ bk, const float* __restrict__ bq,
    const float* __restrict__ bv, const float* __restrict__ bd,
    const float* __restrict__ bgw, const float* __restrict__ bgf,
    const float* __restrict__ x, const float* __restrict__ ln1g,
    const float* __restrict__ ln1b,
    u16* __restrict__ WTQ, u16* __restrict__ WTO, u16* __restrict__ WTPS,
    u16* __restrict__ WT1, u16* __restrict__ WT2, float* __restrict__ BQV,
    u16* __restrict__ XN) {
  int bid = blockIdx.x, tid = threadIdx.x;
  __shared__ float tile[32][33];
  __shared__ float red[8];
  if (bid < 3328) {
    const float* src;
    u16* dst;
    int C, rel, tiles_x;
    if (bid < 256)       { src = Wk;  dst = WTQ;           C = 512;  rel = bid;        tiles_x = 16; }
    else if (bid < 512)  { src = Wq;  dst = WTQ + 262144;  C = 512;  rel = bid - 256;  tiles_x = 16; }
    else if (bid < 768)  { src = Wv;  dst = WTQ + 524288;  C = 512;  rel = bid - 512;  tiles_x = 16; }
    else if (bid < 1024) { src = Wo;  dst = WTO;           C = 512;  rel = bid - 768;  tiles_x = 16; }
    else if (bid < 1280) { src = Wps; dst = WTPS;          C = 512;  rel = bid - 1024; tiles_x = 16; }
    else if (bid < 2304) { src = W1;  dst = WT1;           C = 2048; rel = bid - 1280; tiles_x = 64; }
    else                 { src = W2;  dst = WT2;           C = 512;  rel = bid - 2304; tiles_x = 16; }
    int R = (bid >= 1280 && bid < 2304) ? 512 : (bid >= 2304 ? 2048 : 512);
    int c0 = (rel % tiles_x) * 32, r0 = (rel / tiles_x) * 32;
    int tx = tid & 31, ty = tid >> 5;
#pragma unroll
    for (int i = 0; i < 4; ++i)
      tile[ty + i * 8][tx] = src[(size_t)(r0 + ty + i * 8) * C + c0 + tx];
    __syncthreads();
#pragma unroll
    for (int i = 0; i < 4; ++i)
      dst[(size_t)(c0 + ty + i * 8) * R + r0 + tx] = f2b(tile[tx][ty + i * 8]);
  } else if (bid < 3392) {
    int idx = (bid - 3328) * 256 + tid;
    const int stride = 64 * 256;
    for (int i = idx; i < 128 * 512; i += stride) {
      int local = i >> 9, k = i & 511;
      float v = 0.f;
      if (local < 8) v = Wd[k * 8 + local];
      else if (local < 16) v = Wgw[k * 8 + (local - 8)];
      else if (local < 24) v = Wgf[k * 8 + (local - 16)];
      WTQ[(size_t)(1536 + local) * 512 + k] = f2b(v);
    }
    for (int i = idx; i < 1664; i += stride) {
      float v = 0.f;
      if (i < 512) v = bk[i];
      else if (i < 1024) v = bq[i - 512];
      else if (i < 1536) v = bv[i - 1024];
      else if (i < 1544) v = bd[i - 1536];
      else if (i < 1552) v = bgw[i - 1544];
      else if (i < 1560) v = bgf[i - 1552];
      BQV[i] = v;
    }
  } else {
    int row = bid - 3392;
    ln_row(x + (size_t)row * 512, ln1g, ln1b, XN + (size_t)row * 512, tid, red);
  }
}

// Standalone LN2.
__global__ __launch_bounds__(256) void ln_f32(const float* __restrict__ X,
                                              const float* __restrict__ g,
                                              const float* __restrict__ bt,
                                              u16* __restrict__ Y) {
  __shared__ float red[8];
  ln_row(X + (size_t)blockIdx.x * 512, g, bt, Y + (size_t)blockIdx.x * 512,
         threadIdx.x, red);
}

// ---------------------------------------------------------------------------
// Direct-fragment GEMM: one wave per WMxWN tile, fragments loaded straight
// from global (BT is k-contiguous per row = fragment layout). No LDS, no
// barriers. Manual distance-1 ping-pong; k accumulation order unchanged.
// EPI 1: outf = aux0+v+0.1*aux1
// EPI 2: outb = bf16(gelu(v))
// EPI 3: w = aux0+v; outf = w; outb = bf16(w)
// EPI 4: outf = aux0+v; outf2 = aux1+v
// EPI 5 (QKV, WN=64 == one head): sections by n0: [0,512) l2norm->outb(KB);
//   [512,1024) l2norm->outb2(QB); [1024,1536) tanh->outb3(VB);
//   [1536,1664) raw f32 -> outf(G0, 2048x128).
template <int WM, int WN, int EPI>
__global__ __launch_bounds__(64, 4) void gemm_direct(
    const u16* __restrict__ A, const u16* __restrict__ BT, const float* __restrict__ bias,
    float* __restrict__ outf, float* __restrict__ outf2, u16* __restrict__ outb,
    u16* __restrict__ outb2, u16* __restrict__ outb3,
    const float* __restrict__ aux0, const float* __restrict__ aux1, int M, int N, int K) {
  constexpr int MT = WM / 16, NT = WN / 16;
  const int lane = threadIdx.x;
  const int fr = lane & 15, kq = lane >> 4;
  const int m0 = blockIdx.y * WM, n0 = blockIdx.x * WN;

  const u16* ap[MT];
  const u16* bp[NT];
#pragma unroll
  for (int mt = 0; mt < MT; ++mt)
    ap[mt] = A + (size_t)(m0 + mt * 16 + fr) * K + kq * 8;
#pragma unroll
  for (int nt = 0; nt < NT; ++nt)
    bp[nt] = BT + (size_t)(n0 + nt * 16 + fr) * K + kq * 8;

  floatx4 acc[MT][NT] = {};
  const int nk = K >> 5;
  short8 af[MT], bf[NT], afn[MT], bfn[NT];
#pragma unroll
  for (int mt = 0; mt < MT; ++mt) af[mt] = *(const short8*)(ap[mt]);
#pragma unroll
  for (int nt = 0; nt < NT; ++nt) bf[nt] = *(const short8*)(bp[nt]);

#pragma unroll 2
  for (int kb = 0; kb < nk - 1; ++kb) {
#pragma unroll
    for (int mt = 0; mt < MT; ++mt) afn[mt] = *(const short8*)(ap[mt] + (kb + 1) * 32);
#pragma unroll
    for (int nt = 0; nt < NT; ++nt) bfn[nt] = *(const short8*)(bp[nt] + (kb + 1) * 32);
#pragma unroll
    for (int mt = 0; mt < MT; ++mt)
#pragma unroll
      for (int nt = 0; nt < NT; ++nt)
        acc[mt][nt] =
            __builtin_amdgcn_mfma_f32_16x16x32_bf16(af[mt], bf[nt], acc[mt][nt], 0, 0, 0);
#pragma unroll
    for (int mt = 0; mt < MT; ++mt) af[mt] = afn[mt];
#pragma unroll
    for (int nt = 0; nt < NT; ++nt) bf[nt] = bfn[nt];
  }
#pragma unroll
  for (int mt = 0; mt < MT; ++mt)
#pragma unroll
    for (int nt = 0; nt < NT; ++nt)
      acc[mt][nt] =
          __builtin_amdgcn_mfma_f32_16x16x32_bf16(af[mt], bf[nt], acc[mt][nt], 0, 0, 0);

  const int col = lane & 15;
  const int rbase = (lane >> 4) * 4;

  float vv[MT][NT][4];
#pragma unroll
  for (int nt = 0; nt < NT; ++nt) {
    int gc = n0 + nt * 16 + col;
    float bvv = bias[gc];
#pragma unroll
    for (int mt = 0; mt < MT; ++mt)
#pragma unroll
      for (int r = 0; r < 4; ++r) vv[mt][nt][r] = acc[mt][nt][r] + bvv;
  }

  if constexpr (EPI == 5) {
    const int sec = n0 >> 9;        // 0 K, 1 Q, 2 V, 3 gates
    const int h = (n0 & 511) >> 6;  // head (WN == 64 == head dim)
    if (sec == 3) {
#pragma unroll
      for (int nt = 0; nt < NT; ++nt) {
        int gcl = (n0 - 1536) + nt * 16 + col;
#pragma unroll
        for (int mt = 0; mt < MT; ++mt) {
          int gr = m0 + mt * 16 + rbase;
#pragma unroll
          for (int r = 0; r < 4; ++r)
            outf[(size_t)(gr + r) * 128 + gcl] = vv[mt][nt][r];
        }
      }
    } else if (sec == 2) {
#pragma unroll
      for (int nt = 0; nt < NT; ++nt) {
        int d = nt * 16 + col;
#pragma unroll
        for (int mt = 0; mt < MT; ++mt) {
          int gr = m0 + mt * 16 + rbase;
#pragma unroll
          for (int r = 0; r < 4; ++r) {
            int tok = gr + r;
            int bh = (tok >> 10) * 8 + h;
            outb3[((size_t)bh * 1024 + (tok & 1023)) * 64 + d] =
                f2b(tanhf(vv[mt][nt][r]));
          }
        }
      }
    } else {
      u16* dst = (sec == 0) ? outb : outb2;
#pragma unroll
      for (int mt = 0; mt < MT; ++mt) {
#pragma unroll
        for (int r = 0; r < 4; ++r) {
          // sum of squares over the head's 64 cols: NT partials per lane,
          // then reduce over the 16-lane col group (masks 1,2,4,8).
          float ss = 0.f;
#pragma unroll
          for (int nt = 0; nt < NT; ++nt) ss += vv[mt][nt][r] * vv[mt][nt][r];
          ss += __shfl_xor(ss, 1);
          ss += __shfl_xor(ss, 2);
          ss += __shfl_xor(ss, 4);
          ss += __shfl_xor(ss, 8);
          float rs = 1.0f / fmaxf(sqrtf(ss), 1e-12f);
          int tok = m0 + mt * 16 + rbase + r;
          int bh = (tok >> 10) * 8 + h;
          size_t base = ((size_t)bh * 1024 + (tok & 1023)) * 64;
#pragma unroll
          for (int nt = 0; nt < NT; ++nt)
            dst[base + nt * 16 + col] = f2b(vv[mt][nt][r] * rs);
        }
      }
    }
  } else {
#pragma unroll
    for (int nt = 0; nt < NT; ++nt) {
      int gc = n0 + nt * 16 + col;
#pragma unroll
      for (int mt = 0; mt < MT; ++mt) {
        int gr = m0 + mt * 16 + rbase;
#pragma unroll
        for (int r = 0; r < 4; ++r) {
          size_t idx = (size_t)(gr + r) * N + gc;
          float v = vv[mt][nt][r];
          if constexpr (EPI == 1) {
            outf[idx] = aux0[idx] + v + 0.1f * aux1[idx];
          } else if constexpr (EPI == 2) {
            outb[idx] = f2b(0.5f * v * (1.f + erff(v * 0.70710678118654752f)));
          } else if constexpr (EPI == 3) {
            float w = aux0[idx] + v;
            outf[idx] = w;
            outb[idx] = f2b(w);
          } else if constexpr (EPI == 4) {
            outf[idx] = aux0[idx] + v;
            outf2[idx] = aux1[idx] + v;
          }
        }
      }
    }
  }
}

// ---------------------------------------------------------------------------
// Gates (softplus/sigmoid) + DEC + SVG + serial log-cumsum, one kernel.
__global__ __launch_bounds__(256) void gates_logcum(
    const float* __restrict__ G0, float* __restrict__ DEC, float* __restrict__ SVG,
    float* __restrict__ LC, float* __restrict__ WW) {
  int bh = blockIdx.x;
  int b = bh >> 3, h = bh & 7;
  int tid = threadIdx.x;
  __shared__ float ldec[1024];
#pragma unroll
  for (int tt = 0; tt < 4; ++tt) {
    int t = tt * 256 + tid;
    size_t tok = (size_t)b * 1024 + t;
    float dl = G0[tok * 128 + h];
    float gwl = G0[tok * 128 + 8 + h];
    float gfl = G0[tok * 128 + 16 + h];
    float dd = dl > 20.f ? dl : log1pf(expf(dl));
    float sw = 1.f / (1.f + expf(-gwl));
    float gw = sw * sw;
    float sf = 1.f / (1.f + expf(-gfl));
    float gf = 1.f - sf * sf;
    float dec = fminf(fmaxf(dd * gf, 1e-6f), 0.999f);
    ldec[t] = dec;
    DEC[(size_t)bh * 1024 + t] = dec;
    SVG[(size_t)bh * 1024 + t] = dd * gw;
  }
  __syncthreads();
  if (tid < 64) {
    int lane = tid;
    size_t base = (size_t)bh * 1024 + lane * 16;
    float loc[16];
    float run = 0.f;
#pragma unroll
    for (int i = 0; i < 16; ++i) { run += logf(ldec[lane * 16 + i]); loc[i] = run; }
    float x = run;
#pragma unroll
    for (int o = 1; o < 64; o <<= 1) {
      float v = __shfl_up(x, o);
      if (lane >= o) x += v;
    }
    float excl = x - run;
#pragma unroll
    for (int i = 0; i < 16; ++i) {
      float L = excl + loc[i];
      LC[base + i] = L;
      float c = expf(L);
      WW[base + i] = c / (c + 1e-8f);
    }
  }
}

// ---------------------------------------------------------------------------
// Scan phase 1: per (chunk,h,b) local scan of 32 steps, zero init.
__global__ __launch_bounds__(256, 2) void scan_phase1(
    const u16* __restrict__ KB, const u16* __restrict__ QB, const u16* __restrict__ VB,
    const float* __restrict__ DEC, const float* __restrict__ WW,
    const float* __restrict__ SVG, float* __restrict__ RP, float* __restrict__ SF) {
  int chunk = blockIdx.x, h = blockIdx.y, b = blockIdx.z;
  int bh = b * 8 + h;
  int t0 = chunk * 32;
  __shared__ __align__(16) float sk[2048], sq[2048], sv[2048];
  __shared__ float lsa[32], lsw[32];
  int tid = threadIdx.x;

  const u16* gk = KB + ((size_t)bh * 1024 + t0) * 64;
  const u16* gq = QB + ((size_t)bh * 1024 + t0) * 64;
  const u16* gv = VB + ((size_t)bh * 1024 + t0) * 64;
#pragma unroll
  for (int r = 0; r < 2; ++r) {
    int f = (r * 256 + tid) * 4;
    *(float4*)&sk[f] = b4_to_f4(*(const uint2*)(gk + f));
    *(float4*)&sq[f] = b4_to_f4(*(const uint2*)(gq + f));
    *(float4*)&sv[f] = b4_to_f4(*(const uint2*)(gv + f));
  }
  if (tid < 32) {
    size_t gi = (size_t)bh * 1024 + t0 + tid;
    lsa[tid] = DEC[gi];
    lsw[tid] = WW[gi] * SVG[gi];
  }
  __syncthreads();

  int i = tid >> 2, j0 = (tid & 3) * 16;
  float s[16];
#pragma unroll
  for (int z = 0; z < 16; ++z) s[z] = 0.f;

  for (int t = 0; t < 32; ++t) {
    float a = lsa[t], w = lsw[t];
    float wv = w * sv[t * 64 + i];
    float r = 0.f;
#pragma unroll
    for (int u4 = 0; u4 < 4; ++u4) {
      float4 kv = *(const float4*)&sk[t * 64 + j0 + u4 * 4];
      float4 qv = *(const float4*)&sq[t * 64 + j0 + u4 * 4];
      s[u4 * 4 + 0] = fmaf(a, s[u4 * 4 + 0], wv * kv.x); r = fmaf(s[u4 * 4 + 0], qv.x, r);
      s[u4 * 4 + 1] = fmaf(a, s[u4 * 4 + 1], wv * kv.y); r = fmaf(s[u4 * 4 + 1], qv.y, r);
      s[u4 * 4 + 2] = fmaf(a, s[u4 * 4 + 2], wv * kv.z); r = fmaf(s[u4 * 4 + 2], qv.z, r);
      s[u4 * 4 + 3] = fmaf(a, s[u4 * 4 + 3], wv * kv.w); r = fmaf(s[u4 * 4 + 3], qv.w, r);
    }
    r += __shfl_xor(r, 1);
    r += __shfl_xor(r, 2);
    if ((tid & 3) == 0)
      RP[((size_t)(b * 1024 + t0 + t) * 8 + h) * 64 + i] = r;
  }

  float* Sf = SF + ((size_t)bh * 32 + chunk) * 4096 + i * 64 + j0;
#pragma unroll
  for (int u4 = 0; u4 < 4; ++u4) {
    float4 v;
    v.x = s[u4 * 4 + 0]; v.y = s[u4 * 4 + 1]; v.z = s[u4 * 4 + 2]; v.w = s[u4 * 4 + 3];
    *(float4*)&Sf[u4 * 4] = v;
  }
}

// Scan phase 2: cross-chunk combine over 32 chunks, fully parallel (256 blocks).
__global__ __launch_bounds__(256) void scan_phase2p(const float* __restrict__ SF,
                                                    const float* __restrict__ LC,
                                                    float* __restrict__ SI,
                                                    float* __restrict__ next_mem) {
  int bh = blockIdx.x >> 4;
  int e = (blockIdx.x & 15) * 256 + threadIdx.x;
  float s = 0.f;
  for (int c = 0; c < 32; ++c) {
    SI[((size_t)bh * 32 + c) * 4096 + e] = s;
    float Lend = LC[(size_t)bh * 1024 + c * 32 + 31];
    float Lpre = c ? LC[(size_t)bh * 1024 + c * 32 - 1] : 0.f;
    float P = expf(Lend - Lpre);
    s = fmaf(P, s, SF[((size_t)bh * 32 + c) * 4096 + e]);
  }
  next_mem[(size_t)bh * 4096 + e] = s;
}

// Scan phase 3: add inter-chunk contribution p_t*(Sinit @ q_t); bf16 readout.
__global__ __launch_bounds__(256, 2) void scan_phase3(
    const u16* __restrict__ QB, const float* __restrict__ SI, const float* __restrict__ LC,
    const float* __restrict__ RP, u16* __restrict__ AB) {
  int chunk = blockIdx.x, h = blockIdx.y, b = blockIdx.z;
  int bh = b * 8 + h;
  int t0 = chunk * 32;
  __shared__ __align__(16) float sq[2048];
  __shared__ float sL[32];
  int tid = threadIdx.x;

  const u16* gq = QB + ((size_t)bh * 1024 + t0) * 64;
#pragma unroll
  for (int r = 0; r < 2; ++r) {
    int f = (r * 256 + tid) * 4;
    *(float4*)&sq[f] = b4_to_f4(*(const uint2*)(gq + f));
  }
  if (tid < 32) sL[tid] = LC[(size_t)bh * 1024 + t0 + tid];
  __syncthreads();

  float Lpre = chunk ? LC[(size_t)bh * 1024 + t0 - 1] : 0.f;
  int i = tid >> 2, j0 = (tid & 3) * 16;
  const float* Si = SI + ((size_t)bh * 32 + chunk) * 4096 + i * 64 + j0;
  float S[16];
#pragma unroll
  for (int u4 = 0; u4 < 4; ++u4) {
    float4 v = *(const float4*)&Si[u4 * 4];
    S[u4 * 4 + 0] = v.x; S[u4 * 4 + 1] = v.y; S[u4 * 4 + 2] = v.z; S[u4 * 4 + 3] = v.w;
  }

  for (int t = 0; t < 32; ++t) {
    float p = expf(sL[t] - Lpre);
    float r = 0.f;
#pragma unroll
    for (int u4 = 0; u4 < 4; ++u4) {
      float4 qv = *(const float4*)&sq[t * 64 + j0 + u4 * 4];
      r = fmaf(S[u4 * 4 + 0], qv.x, r);
      r = fmaf(S[u4 * 4 + 1], qv.y, r);
      r = fmaf(S[u4 * 4 + 2], qv.z, r);
      r = fmaf(S[u4 * 4 + 3], qv.w, r);
    }
    r += __shfl_xor(r, 1);
    r += __shfl_xor(r, 2);
    if ((tid & 3) == 0) {
      size_t gi = ((size_t)(b * 1024 + t0 + t) * 8 + h) * 64 + i;
      AB[gi] = f2b(RP[gi] + p * r);
    }
  }
}

// ---------------------------------------------------------------------------
extern "C" void kernel_launch(void* const* d_in, const int* in_sizes, int n_in,
                              void* d_out, int out_size, void* d_ws, size_t ws_size,
                              hipStream_t stream) {
  const float* x = (const float*)d_in[0];
  const float* bmin = (const float*)d_in[1];
  const float* bmax = (const float*)d_in[2];
  const float* motif = (const float*)d_in[3];
  const float* Wk = (const float*)d_in[4];
  const float* bk = (const float*)d_in[5];
  const float* Wq = (const float*)d_in[6];
  const float* bq = (const float*)d_in[7];
  const float* Wv = (const float*)d_in[8];
  const float* bv = (const float*)d_in[9];
  const float* Wo = (const float*)d_in[10];
  const float* bo = (const float*)d_in[11];
  const float* Wd = (const float*)d_in[12];
  const float* bd = (const float*)d_in[13];
  const float* Wgw = (const float*)d_in[14];
  const float* bgw = (const float*)d_in[15];
  const float* Wgf = (const float*)d_in[16];
  const float* bgf = (const float*)d_in[17];
  const float* Wps = (const float*)d_in[18];
  const float* bps = (const float*)d_in[19];
  const float* ln1g = (const float*)d_in[20];
  const float* ln1b = (const float*)d_in[21];
  const float* ln2g = (const float*)d_in[22];
  const float* ln2b = (const float*)d_in[23];
  const float* W1 = (const float*)d_in[24];
  const float* b1 = (const float*)d_in[25];
  const float* W2 = (const float*)d_in[26];
  const float* b2 = (const float*)d_in[27];

  char* ws = (char*)d_ws;
  u16* WTQ = (u16*)(ws + 0);
  u16* WTO = (u16*)(ws + 1703936);
  u16* WT1 = (u16*)(ws + 2228224);
  u16* WT2 = (u16*)(ws + 4325376);
  u16* WTPS = (u16*)(ws + 6422528);
  float* BQV = (float*)(ws + 6946816);
  u16* XN = (u16*)(ws + 6953984);
  float* G0 = (float*)(ws + 9051136);
  u16* KB = (u16*)(ws + 10099712);
  u16* QB = (u16*)(ws + 12196864);
  u16* VB = (u16*)(ws + 14294016);
  float* DEC = (float*)(ws + 16391168);
  float* LC = (float*)(ws + 16456704);
  float* WW = (float*)(ws + 16522240);
  float* SVG = (float*)(ws + 16587776);
  float* RP = (float*)(ws + 16653312);
  float* SF = (float*)(ws + 20847616);
  float* SI = (float*)(ws + 29236224);
  u16* AB = (u16*)(ws + 37624832);
  float* X2 = (float*)(ws + 39721984);
  u16* HB = (u16*)(ws + 43916288);
  u16* MID = (u16*)(ws + 9051136);   // aliases G0..SVG+RP head (dead at FFN1)
  u16* X3B = (u16*)(ws + 20847616);  // aliases SF (dead at FFN2)

  float* out0 = (float*)d_out;
  float* out1 = out0 + 1048576;
  float* out2 = out0 + 1114112;
  float* out3 = out0 + 2162688;

  prep_weights<<<5440, 256, 0, stream>>>(Wk, Wq, Wv, Wo, Wps, W1, W2, Wd, Wgw, Wgf,
                                         bk, bq, bv, bd, bgw, bgf, x, ln1g, ln1b,
                                         WTQ, WTO, WTPS, WT1, WT2, BQV, XN);
  gemm_direct<32, 64, 5><<<dim3(26, 64), 64, 0, stream>>>(
      XN, WTQ, BQV, G0, nullptr, KB, QB, VB, nullptr, nullptr, 2048, 1664, 512);
  gates_logcum<<<16, 256, 0, stream>>>(G0, DEC, SVG, LC, WW);
  scan_phase1<<<dim3(32, 8, 2), 256, 0, stream>>>(KB, QB, VB, DEC, WW, SVG, RP, SF);
  scan_phase2p<<<256, 256, 0, stream>>>(SF, LC, SI, out1);
  scan_phase3<<<dim3(32, 8, 2), 256, 0, stream>>>(QB, SI, LC, RP, AB);

  gemm_direct<16, 32, 1><<<dim3(16, 128), 64, 0, stream>>>(
      AB, WTO, bo, X2, nullptr, nullptr, nullptr, nullptr, x, motif, 2048, 512, 512);
  ln_f32<<<2048, 256, 0, stream>>>(X2, ln2g, ln2b, HB);
  gemm_direct<32, 32, 2><<<dim3(64, 64), 64, 0, stream>>>(
      HB, WT1, b1, nullptr, nullptr, MID, nullptr, nullptr, nullptr, nullptr,
      2048, 2048, 512);
  gemm_direct<16, 32, 3><<<dim3(16, 128), 64, 0, stream>>>(
      MID, WT2, b2, out0, nullptr, X3B, nullptr, nullptr, X2, nullptr,
      2048, 512, 2048);
  gemm_direct<16, 32, 4><<<dim3(16, 128), 64, 0, stream>>>(
      X3B, WTPS, bps, out2, out3, nullptr, nullptr, nullptr, bmin, bmax,
      2048, 512, 512);
}

// Round 11
// 233.421 us; speedup vs baseline: 1.2877x; 1.2877x over previous
//
#include <hip/hip_runtime.h>

// HoloGraphBlockV7 — round 11: revert to round-9 structure (best: 230us);
// QKV+FFN1 GEMMs get a 4-stage BK=32 pipeline (3-iteration DMA lookahead,
// ~450+cyc, covering L2/IC latency) at unchanged 4 blocks/CU occupancy.

typedef unsigned short u16;
typedef unsigned int u32;
typedef __attribute__((ext_vector_type(8))) short short8;
typedef __attribute__((ext_vector_type(4))) float floatx4;

__device__ __forceinline__ float b2f(u16 u) {
  u32 x = ((u32)u) << 16;
  return __uint_as_float(x);
}
__device__ __forceinline__ u16 f2b(float f) {
  u32 x = __float_as_uint(f);
  u32 r = (x + 0x7fffu + ((x >> 16) & 1u)) >> 16;
  return (u16)r;
}
__device__ __forceinline__ float4 b4_to_f4(uint2 u) {
  float4 r;
  r.x = __uint_as_float((u.x & 0xffffu) << 16);
  r.y = __uint_as_float(u.x & 0xffff0000u);
  r.z = __uint_as_float((u.y & 0xffffu) << 16);
  r.w = __uint_as_float(u.y & 0xffff0000u);
  return r;
}

__device__ __forceinline__ void stage16(const u16* g, u16* lds_wave_base) {
  __builtin_amdgcn_global_load_lds((const __attribute__((address_space(1))) void*)g,
                                   (__attribute__((address_space(3))) void*)lds_wave_base,
                                   16, 0, 0);
}

// BK=64 tile stage (round-9): LDS [row][64], chunk m of row r holds k-chunk m^(r&7).
template <int ROWS>
__device__ __forceinline__ void stage_tile64(const u16* __restrict__ G, int ldK, int kb,
                                             u16* lds, int tid) {
#pragma unroll
  for (int r = 0; r < ROWS / 32; ++r) {
    int slot = r * 256 + tid;
    int row = slot >> 3;
    int kwg = (slot & 7) ^ (row & 7);
    stage16(G + (size_t)row * ldK + kb * 64 + kwg * 8,
            lds + (size_t)(r * 256 + (tid >> 6) * 64) * 8);
  }
}

// BK=32 tile stage: LDS [row][32], chunk m of row r holds k-chunk m^((r>>1)&3)
// (max 2-way ds_read aliasing; 64 rows -> exactly 1 inst/thread).
__device__ __forceinline__ void stage_tile32(const u16* __restrict__ G, int ldK, int kb,
                                             u16* lds, int tid) {
  int row = tid >> 2;
  int kwg = (tid & 3) ^ ((row >> 1) & 3);
  stage16(G + (size_t)row * ldK + kb * 32 + kwg * 8,
          lds + (size_t)((tid >> 6) * 64) * 8);
}

// ---------------------------------------------------------------------------
// LayerNorm of one 512-row; 256 threads.
__device__ __forceinline__ void ln_row(const float* __restrict__ xr,
                                       const float* __restrict__ g,
                                       const float* __restrict__ bt,
                                       u16* __restrict__ yr, int tid, float* red) {
  float x0 = xr[tid], x1 = xr[tid + 256];
  float s = x0 + x1, ss = x0 * x0 + x1 * x1;
#pragma unroll
  for (int o = 32; o > 0; o >>= 1) { s += __shfl_xor(s, o); ss += __shfl_xor(ss, o); }
  if ((tid & 63) == 0) { red[tid >> 6] = s; red[4 + (tid >> 6)] = ss; }
  __syncthreads();
  float ts = red[0] + red[1] + red[2] + red[3];
  float tss = red[4] + red[5] + red[6] + red[7];
  float mu = ts * (1.f / 512.f);
  float var = tss * (1.f / 512.f) - mu * mu;
  float rstd = 1.0f / sqrtf(var + 1e-5f);
  yr[tid] = f2b((x0 - mu) * rstd * g[tid] + bt[tid]);
  yr[tid + 256] = f2b((x1 - mu) * rstd * g[tid + 256] + bt[tid + 256]);
}

// ---------------------------------------------------------------------------
// Prep: weight transposes f32->bf16 (0..3327), gate/bias pack (3328..3391),
// LN1 rows (3392..5439).
__global__ __launch_bounds__(256) void prep_weights(
    const float* __restrict__ Wk, const float* __restrict__ Wq,
    const float* __restrict__ Wv, const float* __restrict__ Wo,
    const float* __restrict__ Wps, const float* __restrict__ W1,
    const float* __restrict__ W2, const float* __restrict__ Wd,
    const float* __restrict__ Wgw, const float* __restrict__ Wgf,
    const float* __restrict__ bk, const float* __restrict__ bq,
    const float* __restrict__ bv, const float* __restrict__ bd,
    const float* __restrict__ bgw, const float* __restrict__ bgf,
    const float* __restrict__ x, const float* __restrict__ ln1g,
    const float* __restrict__ ln1b,
    u16* __restrict__ WTQ, u16* __restrict__ WTO, u16* __restrict__ WTPS,
    u16* __restrict__ WT1, u16* __restrict__ WT2, float* __restrict__ BQV,
    u16* __restrict__ XN) {
  int bid = blockIdx.x, tid = threadIdx.x;
  __shared__ float tile[32][33];
  __shared__ float red[8];
  if (bid < 3328) {
    const float* src;
    u16* dst;
    int C, rel, tiles_x;
    if (bid < 256)       { src = Wk;  dst = WTQ;           C = 512;  rel = bid;        tiles_x = 16; }
    else if (bid < 512)  { src = Wq;  dst = WTQ + 262144;  C = 512;  rel = bid - 256;  tiles_x = 16; }
    else if (bid < 768)  { src = Wv;  dst = WTQ + 524288;  C = 512;  rel = bid - 512;  tiles_x = 16; }
    else if (bid < 1024) { src = Wo;  dst = WTO;           C = 512;  rel = bid - 768;  tiles_x = 16; }
    else if (bid < 1280) { src = Wps; dst = WTPS;          C = 512;  rel = bid - 1024; tiles_x = 16; }
    else if (bid < 2304) { src = W1;  dst = WT1;           C = 2048; rel = bid - 1280; tiles_x = 64; }
    else                 { src = W2;  dst = WT2;           C = 512;  rel = bid - 2304; tiles_x = 16; }
    int R = (bid >= 1280 && bid < 2304) ? 512 : (bid >= 2304 ? 2048 : 512);
    int c0 = (rel % tiles_x) * 32, r0 = (rel / tiles_x) * 32;
    int tx = tid & 31, ty = tid >> 5;
#pragma unroll
    for (int i = 0; i < 4; ++i)
      tile[ty + i * 8][tx] = src[(size_t)(r0 + ty + i * 8) * C + c0 + tx];
    __syncthreads();
#pragma unroll
    for (int i = 0; i < 4; ++i)
      dst[(size_t)(c0 + ty + i * 8) * R + r0 + tx] = f2b(tile[tx][ty + i * 8]);
  } else if (bid < 3392) {
    int idx = (bid - 3328) * 256 + tid;
    const int stride = 64 * 256;
    for (int i = idx; i < 128 * 512; i += stride) {
      int local = i >> 9, k = i & 511;
      float v = 0.f;
      if (local < 8) v = Wd[k * 8 + local];
      else if (local < 16) v = Wgw[k * 8 + (local - 8)];
      else if (local < 24) v = Wgf[k * 8 + (local - 16)];
      WTQ[(size_t)(1536 + local) * 512 + k] = f2b(v);
    }
    for (int i = idx; i < 1664; i += stride) {
      float v = 0.f;
      if (i < 512) v = bk[i];
      else if (i < 1024) v = bq[i - 512];
      else if (i < 1536) v = bv[i - 1024];
      else if (i < 1544) v = bd[i - 1536];
      else if (i < 1552) v = bgw[i - 1544];
      else if (i < 1560) v = bgf[i - 1552];
      BQV[i] = v;
    }
  } else {
    int row = bid - 3392;
    ln_row(x + (size_t)row * 512, ln1g, ln1b, XN + (size_t)row * 512, tid, red);
  }
}

// Standalone LN2.
__global__ __launch_bounds__(256) void ln_f32(const float* __restrict__ X,
                                              const float* __restrict__ g,
                                              const float* __restrict__ bt,
                                              u16* __restrict__ Y) {
  __shared__ float red[8];
  ln_row(X + (size_t)blockIdx.x * 512, g, bt, Y + (size_t)blockIdx.x * 512,
         threadIdx.x, red);
}

// ---------------------------------------------------------------------------
// 4-stage BK=32 GEMM for the big shapes (BM=64, N multiple of 64, K=512).
// 3-iteration DMA lookahead at 32KB LDS -> 4 blocks/CU. 2x2 waves, 32x32/wave.
// EPI 2: outb = bf16(gelu(v))
// EPI 5 (QKV): [0,512) l2norm->outb(KB); [512,1024) l2norm->outb2(QB);
//   [1024,1536) tanh->outb3(VB); [1536,1664) raw f32 -> outf(G0, 2048x128).
template <int EPI>
__global__ __launch_bounds__(256, 4) void gemm4s(
    const u16* __restrict__ A, const u16* __restrict__ BT, const float* __restrict__ bias,
    float* __restrict__ outf, u16* __restrict__ outb, u16* __restrict__ outb2,
    u16* __restrict__ outb3, int M, int N, int K) {
  __shared__ __align__(16) u16 As[4][64 * 32];
  __shared__ __align__(16) u16 Bs[4][64 * 32];
  __shared__ float ssb[2][64];
  const int tid = threadIdx.x;
  const int lane = tid & 63, wave = tid >> 6;
  const int wm = wave >> 1, wn = wave & 1;
  const int m0 = blockIdx.y * 64, n0 = blockIdx.x * 64;
  floatx4 acc[2][2] = {};
  const int fr = lane & 15, kq = lane >> 4;
  const int nk = K >> 5;  // 16
  const u16* Ab = A + (size_t)m0 * K;
  const u16* Bb = BT + (size_t)n0 * K;

  stage_tile32(Ab, K, 0, As[0], tid);
  stage_tile32(Bb, K, 0, Bs[0], tid);
  stage_tile32(Ab, K, 1, As[1], tid);
  stage_tile32(Bb, K, 1, Bs[1], tid);
  stage_tile32(Ab, K, 2, As[2], tid);
  stage_tile32(Bb, K, 2, Bs[2], tid);

  for (int kb = 0; kb < nk; ++kb) {
    const int cur = kb & 3;
    if (kb + 3 < nk) {
      const int nxt = (kb + 3) & 3;
      stage_tile32(Ab, K, kb + 3, As[nxt], tid);
      stage_tile32(Bb, K, kb + 3, Bs[nxt], tid);
    }
    int ahead = nk - 1 - kb;
    if (ahead > 3) ahead = 3;
    if (ahead == 3) asm volatile("s_waitcnt vmcnt(6)" ::: "memory");
    else if (ahead == 2) asm volatile("s_waitcnt vmcnt(4)" ::: "memory");
    else if (ahead == 1) asm volatile("s_waitcnt vmcnt(2)" ::: "memory");
    else asm volatile("s_waitcnt vmcnt(0)" ::: "memory");
    asm volatile("s_barrier" ::: "memory");

    short8 af[2], bf[2];
#pragma unroll
    for (int mt = 0; mt < 2; ++mt) {
      int row = wm * 32 + mt * 16 + fr;
      af[mt] = *(const short8*)&As[cur][row * 32 + ((kq ^ ((row >> 1) & 3)) << 3)];
    }
#pragma unroll
    for (int nt = 0; nt < 2; ++nt) {
      int row = wn * 32 + nt * 16 + fr;
      bf[nt] = *(const short8*)&Bs[cur][row * 32 + ((kq ^ ((row >> 1) & 3)) << 3)];
    }
#pragma unroll
    for (int mt = 0; mt < 2; ++mt)
#pragma unroll
      for (int nt = 0; nt < 2; ++nt)
        acc[mt][nt] =
            __builtin_amdgcn_mfma_f32_16x16x32_bf16(af[mt], bf[nt], acc[mt][nt], 0, 0, 0);
    asm volatile("s_waitcnt lgkmcnt(0)" ::: "memory");
    asm volatile("s_barrier" ::: "memory");
  }

  const int col = lane & 15;
  const int rbase = (lane >> 4) * 4;
  float vv[2][2][4];
#pragma unroll
  for (int nt = 0; nt < 2; ++nt) {
    int gc = n0 + wn * 32 + nt * 16 + col;
    float bvv = bias[gc];
#pragma unroll
    for (int mt = 0; mt < 2; ++mt)
#pragma unroll
      for (int r = 0; r < 4; ++r) vv[mt][nt][r] = acc[mt][nt][r] + bvv;
  }

  if constexpr (EPI == 5) {
    const int sec = n0 >> 9;
    const int h = (n0 & 511) >> 6;
    if (sec == 3) {
#pragma unroll
      for (int nt = 0; nt < 2; ++nt) {
        int gcl = (n0 - 1536) + wn * 32 + nt * 16 + col;
#pragma unroll
        for (int mt = 0; mt < 2; ++mt) {
          int gr = m0 + wm * 32 + mt * 16 + rbase;
#pragma unroll
          for (int r = 0; r < 4; ++r)
            outf[(size_t)(gr + r) * 128 + gcl] = vv[mt][nt][r];
        }
      }
    } else if (sec == 2) {
#pragma unroll
      for (int nt = 0; nt < 2; ++nt) {
        int d = wn * 32 + nt * 16 + col;
#pragma unroll
        for (int mt = 0; mt < 2; ++mt) {
          int gr = m0 + wm * 32 + mt * 16 + rbase;
#pragma unroll
          for (int r = 0; r < 4; ++r) {
            int tok = gr + r;
            int bh = (tok >> 10) * 8 + h;
            outb3[((size_t)bh * 1024 + (tok & 1023)) * 64 + d] =
                f2b(tanhf(vv[mt][nt][r]));
          }
        }
      }
    } else {
#pragma unroll
      for (int mt = 0; mt < 2; ++mt) {
#pragma unroll
        for (int r = 0; r < 4; ++r) {
          float ss = vv[mt][0][r] * vv[mt][0][r] + vv[mt][1][r] * vv[mt][1][r];
          ss += __shfl_xor(ss, 1);
          ss += __shfl_xor(ss, 2);
          ss += __shfl_xor(ss, 4);
          ss += __shfl_xor(ss, 8);
          if ((lane & 15) == 0) ssb[wn][wm * 32 + mt * 16 + rbase + r] = ss;
        }
      }
      __syncthreads();
      u16* dst = (sec == 0) ? outb : outb2;
#pragma unroll
      for (int mt = 0; mt < 2; ++mt) {
#pragma unroll
        for (int r = 0; r < 4; ++r) {
          int br = wm * 32 + mt * 16 + rbase + r;
          float tot = ssb[0][br] + ssb[1][br];
          float rs = 1.0f / fmaxf(sqrtf(tot), 1e-12f);
          int tok = m0 + br;
          int bh = (tok >> 10) * 8 + h;
          size_t base = ((size_t)bh * 1024 + (tok & 1023)) * 64;
#pragma unroll
          for (int nt = 0; nt < 2; ++nt) {
            int d = wn * 32 + nt * 16 + col;
            dst[base + d] = f2b(vv[mt][nt][r] * rs);
          }
        }
      }
    }
  } else {
#pragma unroll
    for (int nt = 0; nt < 2; ++nt) {
      int gc = n0 + wn * 32 + nt * 16 + col;
#pragma unroll
      for (int mt = 0; mt < 2; ++mt) {
        int gr = m0 + wm * 32 + mt * 16 + rbase;
#pragma unroll
        for (int r = 0; r < 4; ++r) {
          size_t idx = (size_t)(gr + r) * N + gc;
          float v = vv[mt][nt][r];
          outb[idx] = f2b(0.5f * v * (1.f + erff(v * 0.70710678118654752f)));
        }
      }
    }
  }
}

// ---------------------------------------------------------------------------
// Round-9 2-stage BK=64 GEMM for the N=512 shapes (BM=32, 6 blocks/CU).
// EPI 1: outf = aux0+v+0.1*aux1
// EPI 3: w = aux0+v; outf = w; outb = bf16(w)
// EPI 4: outf = aux0+v; outf2 = aux1+v
template <int EPI>
__global__ __launch_bounds__(256, 6) void gemm2s(
    const u16* __restrict__ A, const u16* __restrict__ BT, const float* __restrict__ bias,
    float* __restrict__ outf, float* __restrict__ outf2, u16* __restrict__ outb,
    const float* __restrict__ aux0, const float* __restrict__ aux1, int M, int N, int K) {
  __shared__ __align__(16) u16 As[2][32 * 64];
  __shared__ __align__(16) u16 Bs[2][64 * 64];
  const int tid = threadIdx.x;
  const int lane = tid & 63, wave = tid >> 6;
  const int wm = wave >> 1, wn = wave & 1;
  const int m0 = blockIdx.y * 32, n0 = blockIdx.x * 64;
  floatx4 acc[2] = {};
  const int fr = lane & 15, kq = lane >> 4;
  const int nk = K >> 6;
  const u16* Ab = A + (size_t)m0 * K;
  const u16* Bb = BT + (size_t)n0 * K;

  stage_tile64<32>(Ab, K, 0, As[0], tid);
  stage_tile64<64>(Bb, K, 0, Bs[0], tid);

  for (int kb = 0; kb < nk; ++kb) {
    const int cur = kb & 1;
    if (kb + 1 < nk) {
      stage_tile64<32>(Ab, K, kb + 1, As[cur ^ 1], tid);
      stage_tile64<64>(Bb, K, kb + 1, Bs[cur ^ 1], tid);
      asm volatile("s_waitcnt vmcnt(3)" ::: "memory");
    } else {
      asm volatile("s_waitcnt vmcnt(0)" ::: "memory");
    }
    asm volatile("s_barrier" ::: "memory");

#pragma unroll
    for (int sub = 0; sub < 2; ++sub) {
      short8 af, bf[2];
      {
        int row = wm * 16 + fr;
        int c = sub * 4 + kq;
        af = *(const short8*)&As[cur][row * 64 + ((c ^ (row & 7)) << 3)];
      }
#pragma unroll
      for (int nt = 0; nt < 2; ++nt) {
        int row = wn * 32 + nt * 16 + fr;
        int c = sub * 4 + kq;
        bf[nt] = *(const short8*)&Bs[cur][row * 64 + ((c ^ (row & 7)) << 3)];
      }
#pragma unroll
      for (int nt = 0; nt < 2; ++nt)
        acc[nt] = __builtin_amdgcn_mfma_f32_16x16x32_bf16(af, bf[nt], acc[nt], 0, 0, 0);
    }
    asm volatile("s_waitcnt lgkmcnt(0)" ::: "memory");
    asm volatile("s_barrier" ::: "memory");
  }

  const int col = lane & 15;
  const int rbase = (lane >> 4) * 4;
#pragma unroll
  for (int nt = 0; nt < 2; ++nt) {
    int gc = n0 + wn * 32 + nt * 16 + col;
    float bvv = bias[gc];
    int gr = m0 + wm * 16 + rbase;
#pragma unroll
    for (int r = 0; r < 4; ++r) {
      size_t idx = (size_t)(gr + r) * N + gc;
      float v = acc[nt][r] + bvv;
      if constexpr (EPI == 1) {
        outf[idx] = aux0[idx] + v + 0.1f * aux1[idx];
      } else if constexpr (EPI == 3) {
        float w = aux0[idx] + v;
        outf[idx] = w;
        outb[idx] = f2b(w);
      } else if constexpr (EPI == 4) {
        outf[idx] = aux0[idx] + v;
        outf2[idx] = aux1[idx] + v;
      }
    }
  }
}

// ---------------------------------------------------------------------------
// Gates (softplus/sigmoid) + DEC + SVG + serial log-cumsum, one kernel.
__global__ __launch_bounds__(256) void gates_logcum(
    const float* __restrict__ G0, float* __restrict__ DEC, float* __restrict__ SVG,
    float* __restrict__ LC, float* __restrict__ WW) {
  int bh = blockIdx.x;
  int b = bh >> 3, h = bh & 7;
  int tid = threadIdx.x;
  __shared__ float ldec[1024];
#pragma unroll
  for (int tt = 0; tt < 4; ++tt) {
    int t = tt * 256 + tid;
    size_t tok = (size_t)b * 1024 + t;
    float dl = G0[tok * 128 + h];
    float gwl = G0[tok * 128 + 8 + h];
    float gfl = G0[tok * 128 + 16 + h];
    float dd = dl > 20.f ? dl : log1pf(expf(dl));
    float sw = 1.f / (1.f + expf(-gwl));
    float gw = sw * sw;
    float sf = 1.f / (1.f + expf(-gfl));
    float gf = 1.f - sf * sf;
    float dec = fminf(fmaxf(dd * gf, 1e-6f), 0.999f);
    ldec[t] = dec;
    DEC[(size_t)bh * 1024 + t] = dec;
    SVG[(size_t)bh * 1024 + t] = dd * gw;
  }
  __syncthreads();
  if (tid < 64) {
    int lane = tid;
    size_t base = (size_t)bh * 1024 + lane * 16;
    float loc[16];
    float run = 0.f;
#pragma unroll
    for (int i = 0; i < 16; ++i) { run += logf(ldec[lane * 16 + i]); loc[i] = run; }
    float x = run;
#pragma unroll
    for (int o = 1; o < 64; o <<= 1) {
      float v = __shfl_up(x, o);
      if (lane >= o) x += v;
    }
    float excl = x - run;
#pragma unroll
    for (int i = 0; i < 16; ++i) {
      float L = excl + loc[i];
      LC[base + i] = L;
      float c = expf(L);
      WW[base + i] = c / (c + 1e-8f);
    }
  }
}

// ---------------------------------------------------------------------------
// Scan phase 1: per (chunk,h,b) local scan of 32 steps, zero init.
__global__ __launch_bounds__(256, 2) void scan_phase1(
    const u16* __restrict__ KB, const u16* __restrict__ QB, const u16* __restrict__ VB,
    const float* __restrict__ DEC, const float* __restrict__ WW,
    const float* __restrict__ SVG, float* __restrict__ RP, float* __restrict__ SF) {
  int chunk = blockIdx.x, h = blockIdx.y, b = blockIdx.z;
  int bh = b * 8 + h;
  int t0 = chunk * 32;
  __shared__ __align__(16) float sk[2048], sq[2048], sv[2048];
  __shared__ float lsa[32], lsw[32];
  int tid = threadIdx.x;

  const u16* gk = KB + ((size_t)bh * 1024 + t0) * 64;
  const u16* gq = QB + ((size_t)bh * 1024 + t0) * 64;
  const u16* gv = VB + ((size_t)bh * 1024 + t0) * 64;
#pragma unroll
  for (int r = 0; r < 2; ++r) {
    int f = (r * 256 + tid) * 4;
    *(float4*)&sk[f] = b4_to_f4(*(const uint2*)(gk + f));
    *(float4*)&sq[f] = b4_to_f4(*(const uint2*)(gq + f));
    *(float4*)&sv[f] = b4_to_f4(*(const uint2*)(gv + f));
  }
  if (tid < 32) {
    size_t gi = (size_t)bh * 1024 + t0 + tid;
    lsa[tid] = DEC[gi];
    lsw[tid] = WW[gi] * SVG[gi];
  }
  __syncthreads();

  int i = tid >> 2, j0 = (tid & 3) * 16;
  float s[16];
#pragma unroll
  for (int z = 0; z < 16; ++z) s[z] = 0.f;

  for (int t = 0; t < 32; ++t) {
    float a = lsa[t], w = lsw[t];
    float wv = w * sv[t * 64 + i];
    float r = 0.f;
#pragma unroll
    for (int u4 = 0; u4 < 4; ++u4) {
      float4 kv = *(const float4*)&sk[t * 64 + j0 + u4 * 4];
      float4 qv = *(const float4*)&sq[t * 64 + j0 + u4 * 4];
      s[u4 * 4 + 0] = fmaf(a, s[u4 * 4 + 0], wv * kv.x); r = fmaf(s[u4 * 4 + 0], qv.x, r);
      s[u4 * 4 + 1] = fmaf(a, s[u4 * 4 + 1], wv * kv.y); r = fmaf(s[u4 * 4 + 1], qv.y, r);
      s[u4 * 4 + 2] = fmaf(a, s[u4 * 4 + 2], wv * kv.z); r = fmaf(s[u4 * 4 + 2], qv.z, r);
      s[u4 * 4 + 3] = fmaf(a, s[u4 * 4 + 3], wv * kv.w); r = fmaf(s[u4 * 4 + 3], qv.w, r);
    }
    r += __shfl_xor(r, 1);
    r += __shfl_xor(r, 2);
    if ((tid & 3) == 0)
      RP[((size_t)(b * 1024 + t0 + t) * 8 + h) * 64 + i] = r;
  }

  float* Sf = SF + ((size_t)bh * 32 + chunk) * 4096 + i * 64 + j0;
#pragma unroll
  for (int u4 = 0; u4 < 4; ++u4) {
    float4 v;
    v.x = s[u4 * 4 + 0]; v.y = s[u4 * 4 + 1]; v.z = s[u4 * 4 + 2]; v.w = s[u4 * 4 + 3];
    *(float4*)&Sf[u4 * 4] = v;
  }
}

// Scan phase 2: cross-chunk combine over 32 chunks, fully parallel (256 blocks).
__global__ __launch_bounds__(256) void scan_phase2p(const float* __restrict__ SF,
                                                    const float* __restrict__ LC,
                                                    float* __restrict__ SI,
                                                    float* __restrict__ next_mem) {
  int bh = blockIdx.x >> 4;
  int e = (blockIdx.x & 15) * 256 + threadIdx.x;
  float s = 0.f;
  for (int c = 0; c < 32; ++c) {
    SI[((size_t)bh * 32 + c) * 4096 + e] = s;
    float Lend = LC[(size_t)bh * 1024 + c * 32 + 31];
    float Lpre = c ? LC[(size_t)bh * 1024 + c * 32 - 1] : 0.f;
    float P = expf(Lend - Lpre);
    s = fmaf(P, s, SF[((size_t)bh * 32 + c) * 4096 + e]);
  }
  next_mem[(size_t)bh * 4096 + e] = s;
}

// Scan phase 3: add inter-chunk contribution p_t*(Sinit @ q_t); bf16 readout.
__global__ __launch_bounds__(256, 2) void scan_phase3(
    const u16* __restrict__ QB, const float* __restrict__ SI, const float* __restrict__ LC,
    const float* __restrict__ RP, u16* __restrict__ AB) {
  int chunk = blockIdx.x, h = blockIdx.y, b = blockIdx.z;
  int bh = b * 8 + h;
  int t0 = chunk * 32;
  __shared__ __align__(16) float sq[2048];
  __shared__ float sL[32];
  int tid = threadIdx.x;

  const u16* gq = QB + ((size_t)bh * 1024 + t0) * 64;
#pragma unroll
  for (int r = 0; r < 2; ++r) {
    int f = (r * 256 + tid) * 4;
    *(float4*)&sq[f] = b4_to_f4(*(const uint2*)(gq + f));
  }
  if (tid < 32) sL[tid] = LC[(size_t)bh * 1024 + t0 + tid];
  __syncthreads();

  float Lpre = chunk ? LC[(size_t)bh * 1024 + t0 - 1] : 0.f;
  int i = tid >> 2, j0 = (tid & 3) * 16;
  const float* Si = SI + ((size_t)bh * 32 + chunk) * 4096 + i * 64 + j0;
  float S[16];
#pragma unroll
  for (int u4 = 0; u4 < 4; ++u4) {
    float4 v = *(const float4*)&Si[u4 * 4];
    S[u4 * 4 + 0] = v.x; S[u4 * 4 + 1] = v.y; S[u4 * 4 + 2] = v.z; S[u4 * 4 + 3] = v.w;
  }

  for (int t = 0; t < 32; ++t) {
    float p = expf(sL[t] - Lpre);
    float r = 0.f;
#pragma unroll
    for (int u4 = 0; u4 < 4; ++u4) {
      float4 qv = *(const float4*)&sq[t * 64 + j0 + u4 * 4];
      r = fmaf(S[u4 * 4 + 0], qv.x, r);
      r = fmaf(S[u4 * 4 + 1], qv.y, r);
      r = fmaf(S[u4 * 4 + 2], qv.z, r);
      r = fmaf(S[u4 * 4 + 3], qv.w, r);
    }
    r += __shfl_xor(r, 1);
    r += __shfl_xor(r, 2);
    if ((tid & 3) == 0) {
      size_t gi = ((size_t)(b * 1024 + t0 + t) * 8 + h) * 64 + i;
      AB[gi] = f2b(RP[gi] + p * r);
    }
  }
}

// ---------------------------------------------------------------------------
extern "C" void kernel_launch(void* const* d_in, const int* in_sizes, int n_in,
                              void* d_out, int out_size, void* d_ws, size_t ws_size,
                              hipStream_t stream) {
  const float* x = (const float*)d_in[0];
  const float* bmin = (const float*)d_in[1];
  const float* bmax = (const float*)d_in[2];
  const float* motif = (const float*)d_in[3];
  const float* Wk = (const float*)d_in[4];
  const float* bk = (const float*)d_in[5];
  const float* Wq = (const float*)d_in[6];
  const float* bq = (const float*)d_in[7];
  const float* Wv = (const float*)d_in[8];
  const float* bv = (const float*)d_in[9];
  const float* Wo = (const float*)d_in[10];
  const float* bo = (const float*)d_in[11];
  const float* Wd = (const float*)d_in[12];
  const float* bd = (const float*)d_in[13];
  const float* Wgw = (const float*)d_in[14];
  const float* bgw = (const float*)d_in[15];
  const float* Wgf = (const float*)d_in[16];
  const float* bgf = (const float*)d_in[17];
  const float* Wps = (const float*)d_in[18];
  const float* bps = (const float*)d_in[19];
  const float* ln1g = (const float*)d_in[20];
  const float* ln1b = (const float*)d_in[21];
  const float* ln2g = (const float*)d_in[22];
  const float* ln2b = (const float*)d_in[23];
  const float* W1 = (const float*)d_in[24];
  const float* b1 = (const float*)d_in[25];
  const float* W2 = (const float*)d_in[26];
  const float* b2 = (const float*)d_in[27];

  char* ws = (char*)d_ws;
  u16* WTQ = (u16*)(ws + 0);
  u16* WTO = (u16*)(ws + 1703936);
  u16* WT1 = (u16*)(ws + 2228224);
  u16* WT2 = (u16*)(ws + 4325376);
  u16* WTPS = (u16*)(ws + 6422528);
  float* BQV = (float*)(ws + 6946816);
  u16* XN = (u16*)(ws + 6953984);
  float* G0 = (float*)(ws + 9051136);
  u16* KB = (u16*)(ws + 10099712);
  u16* QB = (u16*)(ws + 12196864);
  u16* VB = (u16*)(ws + 14294016);
  float* DEC = (float*)(ws + 16391168);
  float* LC = (float*)(ws + 16456704);
  float* WW = (float*)(ws + 16522240);
  float* SVG = (float*)(ws + 16587776);
  float* RP = (float*)(ws + 16653312);
  float* SF = (float*)(ws + 20847616);
  float* SI = (float*)(ws + 29236224);
  u16* AB = (u16*)(ws + 37624832);
  float* X2 = (float*)(ws + 39721984);
  u16* HB = (u16*)(ws + 43916288);
  u16* MID = (u16*)(ws + 9051136);   // aliases G0..SVG+RP head (dead at FFN1)
  u16* X3B = (u16*)(ws + 20847616);  // aliases SF (dead at FFN2)

  float* out0 = (float*)d_out;
  float* out1 = out0 + 1048576;
  float* out2 = out0 + 1114112;
  float* out3 = out0 + 2162688;

  prep_weights<<<5440, 256, 0, stream>>>(Wk, Wq, Wv, Wo, Wps, W1, W2, Wd, Wgw, Wgf,
                                         bk, bq, bv, bd, bgw, bgf, x, ln1g, ln1b,
                                         WTQ, WTO, WTPS, WT1, WT2, BQV, XN);
  gemm4s<5><<<dim3(26, 32), 256, 0, stream>>>(XN, WTQ, BQV, G0, KB, QB, VB,
                                              2048, 1664, 512);
  gates_logcum<<<16, 256, 0, stream>>>(G0, DEC, SVG, LC, WW);
  scan_phase1<<<dim3(32, 8, 2), 256, 0, stream>>>(KB, QB, VB, DEC, WW, SVG, RP, SF);
  scan_phase2p<<<256, 256, 0, stream>>>(SF, LC, SI, out1);
  scan_phase3<<<dim3(32, 8, 2), 256, 0, stream>>>(QB, SI, LC, RP, AB);

  gemm2s<1><<<dim3(8, 64), 256, 0, stream>>>(AB, WTO, bo, X2, nullptr, nullptr,
                                             x, motif, 2048, 512, 512);
  ln_f32<<<2048, 256, 0, stream>>>(X2, ln2g, ln2b, HB);
  gemm4s<2><<<dim3(32, 32), 256, 0, stream>>>(HB, WT1, b1, nullptr, MID, nullptr,
                                              nullptr, 2048, 2048, 512);
  gemm2s<3><<<dim3(8, 64), 256, 0, stream>>>(MID, WT2, b2, out0, nullptr, X3B,
                                             X2, nullptr, 2048, 512, 2048);
  gemm2s<4><<<dim3(8, 64), 256, 0, stream>>>(X3B, WTPS, bps, out2, out3, nullptr,
                                             bmin, bmax, 2048, 512, 512);
}